// Round 6
// baseline (144.657 us; speedup 1.0000x reference)
//
#include <hip/hip_runtime.h>
#include <math.h>

#define NB 16
#define CF 64
#define LL 16384
#define GG 8
#define NH 2
#define CHN 64          // chunk length
#define NCH 256         // chunks per batch
#define NGRP 16         // groups of 16 chunks

static constexpr size_t OFF_GT = 0;
static constexpr size_t OFF_C  = OFF_GT + (size_t)NB*LL*GG;
static constexpr size_t OFF_YL = OFF_C  + (size_t)NB*LL*16;
static constexpr size_t OFF_CA = OFF_YL + (size_t)NB*LL*16;
static constexpr size_t OFF_U2 = OFF_CA + (size_t)NB*LL*NH;
static constexpr size_t OFF_AC = OFF_U2 + (size_t)NB*NCH*256;
static constexpr size_t OFF_PH = OFF_AC + (size_t)NB*NCH*NH;
static constexpr size_t OFF_CP = OFF_PH + (size_t)NB*NCH*256;
static constexpr size_t OFF_UG = OFF_CP + (size_t)NB*NCH*NH;
static constexpr size_t OFF_AG = OFF_UG + (size_t)NB*NGRP*256;
static constexpr size_t OFF_GH = OFF_AG + (size_t)NB*NGRP*NH;
static constexpr size_t OFF_G2 = OFF_GH + (size_t)NB*NGRP*256;
static constexpr size_t WS_FLOATS = OFF_G2 + (size_t)NB*LL*GG;

__device__ __forceinline__ float siluf(float v){ return v / (1.f + __expf(-v)); }
__device__ __forceinline__ float softplusf(float v){ return v > 20.f ? v : log1pf(__expf(v)); }

__device__ __forceinline__ void load8(float* d, const float* p){
    float4 a = ((const float4*)p)[0];
    float4 b = ((const float4*)p)[1];
    d[0]=a.x; d[1]=a.y; d[2]=a.z; d[3]=a.w;
    d[4]=b.x; d[5]=b.y; d[6]=b.z; d[7]=b.w;
}
__device__ __forceinline__ void load16(float* d, const float* p){
    load8(d, p); load8(d+8, p+8);
}

// K1a: tokenize x -> gt.
__global__ __launch_bounds__(256) void k1a_tok(
    const float* __restrict__ x, const float* __restrict__ tok_w,
    const float* __restrict__ tok_b, float* __restrict__ gtw)
{
    __shared__ float s_tok[GG*CF];
    int tid = threadIdx.x;
    int b  = blockIdx.x >> 4;
    int ck = blockIdx.x & 15;
    int l0 = (ck << 10) + (tid << 2);
    for (int i = tid; i < GG*CF; i += 256) s_tok[i] = tok_w[i];
    __syncthreads();
    float acc[4][GG];
    #pragma unroll
    for (int r = 0; r < 4; ++r)
        #pragma unroll
        for (int g = 0; g < GG; ++g) acc[r][g] = tok_b[g];
    const float* xb = x + (size_t)b*CF*LL + l0;
    #pragma unroll 8
    for (int c = 0; c < CF; ++c) {
        float4 xv = *(const float4*)(xb + (size_t)c*LL);
        float xa[4] = {xv.x, xv.y, xv.z, xv.w};
        #pragma unroll
        for (int g = 0; g < GG; ++g) {
            float w = s_tok[g*CF + c];
            #pragma unroll
            for (int r = 0; r < 4; ++r) acc[r][g] = fmaf(xa[r], w, acc[r][g]);
        }
    }
    float* gp = gtw + ((size_t)b*LL + l0)*GG;
    #pragma unroll
    for (int r = 0; r < 4; ++r) {
        ((float4*)gp)[r*2+0] = make_float4(acc[r][0],acc[r][1],acc[r][2],acc[r][3]);
        ((float4*)gp)[r*2+1] = make_float4(acc[r][4],acc[r][5],acc[r][6],acc[r][7]);
    }
}

// K2: chunked SSD. Block = (b, chunk of 64). No sequential scan: G = C B^T, decay
// mask via log-cumsum, Y = (L.G.dt) X, chunk end-state via weighted sums.
__global__ __launch_bounds__(256, 4) void k2_ssd(
    const float* __restrict__ gtw,
    const float* __restrict__ ipw, const float* __restrict__ ipb,
    const float* __restrict__ cw, const float* __restrict__ cb,
    const float* __restrict__ A_log, const float* __restrict__ dt_bias,
    const float* __restrict__ Dv,
    float* __restrict__ cmw, float* __restrict__ ylw, float* __restrict__ caw,
    float* __restrict__ U2w, float* __restrict__ Acw)
{
    __shared__ float s_x [64][20];   // xr rows (float4-aligned)
    __shared__ float s_Ct[64][17];   // C rows (scalar access)
    __shared__ float s_BT[16][68];   // B transposed [n][s]
    __shared__ float s_G [64][68];   // G[t][s] = C_t . B_s
    __shared__ float s_dt[64][2], s_nda[64][2], s_la[64][2], s_w[64][2];
    __shared__ float s_ipw[48*8], s_ipb2[48], s_cw2[144], s_cb2[48], s_wdt[16];

    int tid = threadIdx.x;
    int b = blockIdx.x >> 8, c = blockIdx.x & 255;
    for (int i = tid; i < 384; i += 256) s_ipw[i] = ipw[128 + i];
    if (tid < 48) { s_ipb2[tid] = ipb[16 + tid]; s_cb2[tid] = cb[tid]; }
    else if (tid >= 64 && tid < 208) s_cw2[tid - 64] = cw[tid - 64];
    else if (tid >= 224 && tid < 240) s_wdt[tid - 224] = ipw[512 + (tid - 224)];
    __syncthreads();

    float a0e = __expf(A_log[0]), a1e = __expf(A_log[1]);
    float dtb0 = dt_bias[0], dtb1 = dt_bias[1];
    float bdt0 = ipb[64], bdt1 = ipb[65];
    float D0 = Dv[0], D1 = Dv[1];

    // ---- staging: 4 threads per row, 12 channels each ----
    {
        int r = tid >> 2, sub = tid & 3;
        int l = c*CHN + r;
        size_t gb = ((size_t)b*LL + l)*GG;
        float g0[8], g1[8], g2v[8];
        #pragma unroll
        for (int g = 0; g < 8; ++g) { g1[g] = 0.f; g2v[g] = 0.f; }
        load8(g0, gtw + gb);
        if (l >= 1) load8(g1, gtw + gb - GG);
        if (l >= 2) load8(g2v, gtw + gb - 2*GG);
        #pragma unroll
        for (int k = 0; k < 12; ++k) {
            int ch = sub*12 + k;
            float bia = s_ipb2[ch];
            float tA = bia, tB = bia, tC = bia;
            #pragma unroll
            for (int g = 0; g < 8; ++g) {
                float wv = s_ipw[ch*8+g];
                tA = fmaf(g0[g],  wv, tA);
                tB = fmaf(g1[g],  wv, tB);
                tC = fmaf(g2v[g], wv, tC);
            }
            if (l < 1) tB = 0.f;
            if (l < 2) tC = 0.f;
            float a = s_cb2[ch];
            a = fmaf(tC, s_cw2[ch*3+0], a);
            a = fmaf(tB, s_cw2[ch*3+1], a);
            a = fmaf(tA, s_cw2[ch*3+2], a);
            float v = siluf(a);
            if (ch < 16)      s_x[r][ch] = v;
            else if (ch < 32) s_BT[ch-16][r] = v;
            else              s_Ct[r][ch-32] = v;
        }
        if (sub == 0) {
            float d0 = bdt0, d1 = bdt1;
            #pragma unroll
            for (int g = 0; g < 8; ++g) {
                d0 = fmaf(g0[g], s_wdt[g],   d0);
                d1 = fmaf(g0[g], s_wdt[8+g], d1);
            }
            float dt0 = softplusf(d0 + dtb0), dt1 = softplusf(d1 + dtb1);
            s_dt[r][0] = dt0; s_dt[r][1] = dt1;
            s_nda[r][0] = -dt0*a0e; s_nda[r][1] = -dt1*a1e;
        }
    }
    __syncthreads();
    // ---- cmw write (coalesced) ----
    {
        int rr = tid >> 2, q = tid & 3;
        float4 cv = make_float4(s_Ct[rr][q*4+0], s_Ct[rr][q*4+1],
                                s_Ct[rr][q*4+2], s_Ct[rr][q*4+3]);
        ((float4*)(cmw + ((size_t)b*LL + c*CHN + rr)*16))[q] = cv;
    }
    // ---- log-cumsum by wave 0 ----
    if (tid < 64) {
        int rr = tid;
        float v0 = s_nda[rr][0], v1 = s_nda[rr][1];
        #pragma unroll
        for (int off = 1; off < 64; off <<= 1) {
            float t0 = __shfl_up(v0, off);
            float t1 = __shfl_up(v1, off);
            if (rr >= off) { v0 += t0; v1 += t1; }
        }
        s_la[rr][0] = v0; s_la[rr][1] = v1;
        *(float2*)(caw + ((size_t)b*LL + c*CHN + rr)*2) =
            make_float2(__expf(v0), __expf(v1));
        float f0 = __shfl(v0, 63), f1 = __shfl(v1, 63);
        s_w[rr][0] = __expf(f0 - v0) * s_dt[rr][0];
        s_w[rr][1] = __expf(f1 - v1) * s_dt[rr][1];
        if (rr == 63)
            *(float2*)(Acw + ((size_t)b*NCH + c)*2) = make_float2(__expf(f0), __expf(f1));
    }
    __syncthreads();
    // ---- G = C B^T : thread owns 4x4 tile ----
    {
        int t0 = (tid >> 4) * 4, s0 = (tid & 15) * 4;
        float acc[4][4];
        #pragma unroll
        for (int i = 0; i < 4; ++i)
            #pragma unroll
            for (int j = 0; j < 4; ++j) acc[i][j] = 0.f;
        #pragma unroll
        for (int n = 0; n < 16; ++n) {
            float c0 = s_Ct[t0+0][n], c1 = s_Ct[t0+1][n];
            float c2 = s_Ct[t0+2][n], c3 = s_Ct[t0+3][n];
            float4 bb = *(const float4*)&s_BT[n][s0];
            float bv[4] = {bb.x, bb.y, bb.z, bb.w};
            #pragma unroll
            for (int j = 0; j < 4; ++j) {
                acc[0][j] = fmaf(c0, bv[j], acc[0][j]);
                acc[1][j] = fmaf(c1, bv[j], acc[1][j]);
                acc[2][j] = fmaf(c2, bv[j], acc[2][j]);
                acc[3][j] = fmaf(c3, bv[j], acc[3][j]);
            }
        }
        #pragma unroll
        for (int i = 0; i < 4; ++i)
            *(float4*)&s_G[t0+i][s0] = make_float4(acc[i][0],acc[i][1],acc[i][2],acc[i][3]);
    }
    __syncthreads();
    // ---- Y: thread = (t = tid>>2, hq = tid&3) -> 4 outputs Y[t][hq*4..+3] ----
    {
        int t = tid >> 2, hq = tid & 3, hh = hq >> 1;
        int pbase = hq * 4;
        float lat = s_la[t][hh];
        float Dh = hh ? D1 : D0;
        float4 xt = *(const float4*)&s_x[t][pbase];
        float4 acc;
        acc.x = Dh*xt.x; acc.y = Dh*xt.y; acc.z = Dh*xt.z; acc.w = Dh*xt.w;
        int send = ((tid >> 6) << 4) + 15;   // wave-uniform bound
        for (int s = 0; s <= send; ++s) {
            float e = __expf(lat - s_la[s][hh]);
            float m = (s <= t) ? e * s_G[t][s] * s_dt[s][hh] : 0.f;
            float4 xs = *(const float4*)&s_x[s][pbase];
            acc.x = fmaf(m, xs.x, acc.x);
            acc.y = fmaf(m, xs.y, acc.y);
            acc.z = fmaf(m, xs.z, acc.z);
            acc.w = fmaf(m, xs.w, acc.w);
        }
        ((float4*)(ylw + ((size_t)b*LL + c*CHN)*16))[tid] = acc;
    }
    // ---- chunk end-state: thread = (he, p, n) ----
    {
        int he = tid >> 7, pp = (tid >> 4) & 7, n = tid & 15;
        float hsum = 0.f;
        #pragma unroll 8
        for (int s = 0; s < 64; ++s)
            hsum = fmaf(s_w[s][he] * s_x[s][he*8+pp], s_BT[n][s], hsum);
        U2w[(((size_t)b*NCH + c) << 8) + tid] = hsum;
    }
}

// K4c1: scan 16 chunks within each group.
__global__ void k4c1(const float* __restrict__ U2w, const float* __restrict__ Acw,
                     float* __restrict__ phw, float* __restrict__ cpw,
                     float* __restrict__ Ugw, float* __restrict__ Agw)
{
    int b = blockIdx.x >> 4, grp = blockIdx.x & 15;
    int e = threadIdx.x, he = e >> 7;
    float h = 0.f, cp = 1.f;
    #pragma unroll
    for (int j = 0; j < 16; ++j) {
        int ch = grp*16 + j;
        size_t ui = (((size_t)b*NCH + ch) << 8) + e;
        phw[ui] = h;
        if ((e & 127) == 0) cpw[((size_t)b*NCH + ch)*2 + he] = cp;
        float A = Acw[((size_t)b*NCH + ch)*2 + he];
        h = fmaf(A, h, U2w[ui]);
        cp *= A;
    }
    Ugw[(((size_t)b*NGRP + grp) << 8) + e] = h;
    if ((e & 127) == 0) Agw[((size_t)b*NGRP + grp)*2 + he] = cp;
}

// K4c2: scan 16 group summaries.
__global__ void k4c2(const float* __restrict__ Ugw, const float* __restrict__ Agw,
                     float* __restrict__ ghw)
{
    int b = blockIdx.x, e = threadIdx.x, he = e >> 7;
    float h = 0.f;
    #pragma unroll
    for (int g = 0; g < 16; ++g) {
        ghw[(((size_t)b*NGRP + g) << 8) + e] = h;
        h = fmaf(Agw[((size_t)b*NGRP + g)*2 + he], h, Ugw[(((size_t)b*NGRP + g) << 8) + e]);
    }
}

// K5a: hin reconstruction + correction + silu(z) gate + RMSNorm + out proj + gt residual -> g2
__global__ __launch_bounds__(256, 4) void k5a_epi(
    const float* __restrict__ gtw, const float* __restrict__ cmw,
    const float* __restrict__ ylw, const float* __restrict__ caw,
    const float* __restrict__ phw, const float* __restrict__ cpw,
    const float* __restrict__ ghw,
    const float* __restrict__ ipw, const float* __restrict__ ipb,
    const float* __restrict__ norm_w,
    const float* __restrict__ out_w, const float* __restrict__ out_b,
    float* __restrict__ g2w)
{
    __shared__ float s_hin[4][256];
    __shared__ float s_zw[16*GG], s_ow[GG*16];
    int tid = threadIdx.x;
    int b  = blockIdx.x >> 6;
    int ck = blockIdx.x & 63;           // 256-row block = 4 chunks of 64
    int grpg = ck >> 2;
    float gh = ghw[(((size_t)b*NGRP + grpg) << 8) + tid];
    #pragma unroll
    for (int k = 0; k < 4; ++k) {
        int chn = ck*4 + k;
        float cpv = cpw[((size_t)b*NCH + chn)*2 + (tid >> 7)];
        s_hin[k][tid] = fmaf(cpv, gh, phw[(((size_t)b*NCH + chn) << 8) + tid]);
    }
    if (tid < 128) s_zw[tid] = ipw[tid];
    else s_ow[tid-128] = out_w[tid-128];
    __syncthreads();
    size_t pb = (size_t)b*LL + (ck<<8) + tid;
    int sub = tid >> 6;
    float gv[8]; load8(gv, gtw + pb*GG);
    float Cv[16], ylv[16];
    load16(Cv,  cmw + pb*16);
    load16(ylv, ylw + pb*16);
    float2 ca = *(const float2*)(caw + pb*2);
    float vv[16], ss = 0.f;
    #pragma unroll
    for (int hp = 0; hp < 16; ++hp) {
        float dot = 0.f;
        #pragma unroll
        for (int nn = 0; nn < 16; ++nn)
            dot = fmaf(Cv[nn], s_hin[sub][(hp>>3)*128 + (hp&7)*16 + nn], dot);
        float zz = ipb[hp];
        #pragma unroll
        for (int g = 0; g < GG; ++g) zz = fmaf(gv[g], s_zw[hp*GG+g], zz);
        float y = fmaf((hp>>3) ? ca.y : ca.x, dot, ylv[hp]);
        float w = y * siluf(zz);
        vv[hp] = w; ss = fmaf(w, w, ss);
    }
    float rn = rsqrtf(ss*(1.f/16.f) + 1e-5f);
    float o[8];
    #pragma unroll
    for (int g = 0; g < GG; ++g) o[g] = out_b[g] + gv[g];
    #pragma unroll
    for (int hp = 0; hp < 16; ++hp) {
        float wv = vv[hp] * rn * norm_w[hp];
        #pragma unroll
        for (int g = 0; g < GG; ++g) o[g] = fmaf(wv, s_ow[g*16+hp], o[g]);
    }
    float* gp = g2w + pb*GG;
    ((float4*)gp)[0] = make_float4(o[0],o[1],o[2],o[3]);
    ((float4*)gp)[1] = make_float4(o[4],o[5],o[6],o[7]);
}

// K5b: out = x + detok(g2) + detok_b.
__global__ __launch_bounds__(256, 4) void k5b_detok(
    const float* __restrict__ x, const float* __restrict__ g2w,
    const float* __restrict__ dkw, const float* __restrict__ dkb,
    float* __restrict__ outp)
{
    __shared__ float s_dw[CF*GG];
    __shared__ float s_db[CF];
    int tid = threadIdx.x;
    int b  = blockIdx.x >> 4;
    int ck = blockIdx.x & 15;
    int l0 = (ck << 10) + (tid << 2);
    for (int i = tid; i < CF*GG; i += 256) s_dw[i] = dkw[i];
    if (tid < CF) s_db[tid] = dkb[tid];
    __syncthreads();
    float g2v[4][8];
    const float* gp = g2w + ((size_t)b*LL + l0)*GG;
    #pragma unroll
    for (int r = 0; r < 4; ++r) load8(g2v[r], gp + r*GG);
    const float* xb = x + (size_t)b*CF*LL + l0;
    float* ob = outp + (size_t)b*CF*LL + l0;
    #pragma unroll 4
    for (int c = 0; c < CF; ++c) {
        float4 xv = *(const float4*)(xb + (size_t)c*LL);
        float bias = s_db[c];
        float oa[4] = {xv.x+bias, xv.y+bias, xv.z+bias, xv.w+bias};
        #pragma unroll
        for (int g = 0; g < GG; ++g) {
            float w = s_dw[c*GG+g];
            #pragma unroll
            for (int r = 0; r < 4; ++r) oa[r] = fmaf(g2v[r][g], w, oa[r]);
        }
        *(float4*)(ob + (size_t)c*LL) = make_float4(oa[0],oa[1],oa[2],oa[3]);
    }
}

extern "C" void kernel_launch(void* const* d_in, const int* in_sizes, int n_in,
                              void* d_out, int out_size, void* d_ws, size_t ws_size,
                              hipStream_t stream) {
    const float* x       = (const float*)d_in[0];
    const float* tok_w   = (const float*)d_in[1];
    const float* tok_b   = (const float*)d_in[2];
    const float* detok_w = (const float*)d_in[3];
    const float* detok_b = (const float*)d_in[4];
    const float* ipw     = (const float*)d_in[5];
    const float* ipb     = (const float*)d_in[6];
    const float* cw      = (const float*)d_in[7];
    const float* cb      = (const float*)d_in[8];
    const float* A_log   = (const float*)d_in[9];
    const float* Dv      = (const float*)d_in[10];
    const float* dt_bias = (const float*)d_in[11];
    const float* norm_w  = (const float*)d_in[12];
    const float* out_w   = (const float*)d_in[13];
    const float* out_b   = (const float*)d_in[14];
    float* ws = (float*)d_ws;
    float* outp = (float*)d_out;

    if (ws_size < WS_FLOATS * sizeof(float)) return;

    k1a_tok<<<NB*16, 256, 0, stream>>>(x, tok_w, tok_b, ws+OFF_GT);
    k2_ssd<<<NB*NCH, 256, 0, stream>>>(ws+OFF_GT, ipw, ipb, cw, cb,
        A_log, dt_bias, Dv, ws+OFF_C, ws+OFF_YL, ws+OFF_CA, ws+OFF_U2, ws+OFF_AC);
    k4c1<<<NB*NGRP, 256, 0, stream>>>(ws+OFF_U2, ws+OFF_AC,
        ws+OFF_PH, ws+OFF_CP, ws+OFF_UG, ws+OFF_AG);
    k4c2<<<NB, 256, 0, stream>>>(ws+OFF_UG, ws+OFF_AG, ws+OFF_GH);
    k5a_epi<<<NB*64, 256, 0, stream>>>(ws+OFF_GT, ws+OFF_C, ws+OFF_YL, ws+OFF_CA,
        ws+OFF_PH, ws+OFF_CP, ws+OFF_GH, ipw, ipb, norm_w, out_w, out_b, ws+OFF_G2);
    k5b_detok<<<NB*16, 256, 0, stream>>>(x, ws+OFF_G2, detok_w, detok_b, outp);
}

// Round 7
// 129.796 us; speedup vs baseline: 1.1145x; 1.1145x over previous
//
#include <hip/hip_runtime.h>
#include <math.h>

#define NB 16
#define CF 64
#define LL 16384
#define GG 8
#define NH 2
#define CHN 64          // chunk length
#define NCH 256         // chunks per batch
#define NGRP 16         // groups of 16 chunks

static constexpr size_t OFF_GT = 0;
static constexpr size_t OFF_C  = OFF_GT + (size_t)NB*LL*GG;
static constexpr size_t OFF_YL = OFF_C  + (size_t)NB*LL*16;
static constexpr size_t OFF_CA = OFF_YL + (size_t)NB*LL*16;
static constexpr size_t OFF_U2 = OFF_CA + (size_t)NB*LL*NH;
static constexpr size_t OFF_AC = OFF_U2 + (size_t)NB*NCH*256;
static constexpr size_t OFF_PH = OFF_AC + (size_t)NB*NCH*NH;
static constexpr size_t OFF_CP = OFF_PH + (size_t)NB*NCH*256;
static constexpr size_t OFF_UG = OFF_CP + (size_t)NB*NCH*NH;
static constexpr size_t OFF_AG = OFF_UG + (size_t)NB*NGRP*256;
static constexpr size_t OFF_GH = OFF_AG + (size_t)NB*NGRP*NH;
static constexpr size_t OFF_G2 = OFF_GH + (size_t)NB*NGRP*256;
static constexpr size_t WS_FLOATS = OFF_G2 + (size_t)NB*LL*GG;

typedef float f32x4 __attribute__((ext_vector_type(4)));
typedef short bf16x8 __attribute__((ext_vector_type(8)));

__device__ __forceinline__ float siluf(float v){ return v / (1.f + __expf(-v)); }
__device__ __forceinline__ float softplusf(float v){ return v > 20.f ? v : log1pf(__expf(v)); }

__device__ __forceinline__ unsigned short f2bf(float f){
    unsigned int u = __float_as_uint(f);
    u += 0x7fffu + ((u >> 16) & 1u);
    return (unsigned short)(u >> 16);
}
__device__ __forceinline__ float bf2f(unsigned short s){
    return __uint_as_float(((unsigned int)s) << 16);
}

__device__ __forceinline__ void load8(float* d, const float* p){
    float4 a = ((const float4*)p)[0];
    float4 b = ((const float4*)p)[1];
    d[0]=a.x; d[1]=a.y; d[2]=a.z; d[3]=a.w;
    d[4]=b.x; d[5]=b.y; d[6]=b.z; d[7]=b.w;
}
__device__ __forceinline__ void load16(float* d, const float* p){
    load8(d, p); load8(d+8, p+8);
}

// K1a: tokenize x -> gt.  1024 blocks x 64 threads (16 blocks/CU), 4 l per thread.
__global__ __launch_bounds__(64) void k1a_tok(
    const float* __restrict__ x, const float* __restrict__ tok_w,
    const float* __restrict__ tok_b, float* __restrict__ gtw)
{
    __shared__ float s_tok[GG*CF];
    int tid = threadIdx.x;
    int b  = blockIdx.x >> 6;
    int ck = blockIdx.x & 63;
    int l0 = (ck << 8) + (tid << 2);
    for (int i = tid; i < GG*CF; i += 64) s_tok[i] = tok_w[i];
    __syncthreads();
    float acc[4][GG];
    #pragma unroll
    for (int r = 0; r < 4; ++r)
        #pragma unroll
        for (int g = 0; g < GG; ++g) acc[r][g] = tok_b[g];
    const float* xb = x + (size_t)b*CF*LL + l0;
    #pragma unroll 8
    for (int c = 0; c < CF; ++c) {
        float4 xv = *(const float4*)(xb + (size_t)c*LL);
        float xa[4] = {xv.x, xv.y, xv.z, xv.w};
        #pragma unroll
        for (int g = 0; g < GG; ++g) {
            float w = s_tok[g*CF + c];
            #pragma unroll
            for (int r = 0; r < 4; ++r) acc[r][g] = fmaf(xa[r], w, acc[r][g]);
        }
    }
    float* gp = gtw + ((size_t)b*LL + l0)*GG;
    #pragma unroll
    for (int r = 0; r < 4; ++r) {
        ((float4*)gp)[r*2+0] = make_float4(acc[r][0],acc[r][1],acc[r][2],acc[r][3]);
        ((float4*)gp)[r*2+1] = make_float4(acc[r][4],acc[r][5],acc[r][6],acc[r][7]);
    }
}

// K2: chunked SSD with MFMA. Block = (b, chunk of 64).
// G = C.B^T, M~ = mask*exp*dt*G (bf16), Y = M~ . X + D*x via MFMA; state via MFMA.
__global__ __launch_bounds__(256, 3) void k2_ssd(
    const float* __restrict__ gtw,
    const float* __restrict__ ipw, const float* __restrict__ ipb,
    const float* __restrict__ cw, const float* __restrict__ cb,
    const float* __restrict__ A_log, const float* __restrict__ dt_bias,
    const float* __restrict__ Dv,
    float* __restrict__ cmw, float* __restrict__ ylw, float* __restrict__ caw,
    float* __restrict__ U2w, float* __restrict__ Acw)
{
    // bf16 operand tiles (rows 16B-aligned)
    __shared__ __align__(16) unsigned short Cbf[64*40];   // C[t][n], cols 16..31 zero
    __shared__ __align__(16) unsigned short Bbf[64*40];   // B[s][n], cols 16..31 zero
    __shared__ __align__(16) unsigned short XTbf[16*72];  // x^T[p][s]
    __shared__ __align__(16) unsigned short BTbf[16*72];  // B^T[n][s]
    __shared__ __align__(16) unsigned short WXbf[16*72];  // (w*x)^T[p][s]
    __shared__ __align__(16) unsigned short M0[64*72];    // M~ head0 [t][s]
    __shared__ __align__(16) unsigned short M1[64*72];    // M~ head1 [t][s]
    __shared__ __align__(16) float s_xf[64*20];           // x fp32 [r][p]
    __shared__ float s_dt[64][2], s_nda[64][2], s_la[64][2], s_w[64][2];
    __shared__ float s_ipw[48*8], s_ipb2[48], s_cw2[144], s_cb2[48], s_wdt[16];

    int tid = threadIdx.x;
    int b = blockIdx.x >> 8, c = blockIdx.x & 255;
    for (int i = tid; i < 384; i += 256) s_ipw[i] = ipw[128 + i];
    if (tid < 48) { s_ipb2[tid] = ipb[16 + tid]; s_cb2[tid] = cb[tid]; }
    else if (tid >= 64 && tid < 208) s_cw2[tid - 64] = cw[tid - 64];
    else if (tid >= 224 && tid < 240) s_wdt[tid - 224] = ipw[512 + (tid - 224)];
    __syncthreads();

    float a0e = __expf(A_log[0]), a1e = __expf(A_log[1]);
    float dtb0 = dt_bias[0], dtb1 = dt_bias[1];
    float bdt0 = ipb[64], bdt1 = ipb[65];
    float D0 = Dv[0], D1 = Dv[1];

    // ---- staging: in_proj + conv3 + silu; 4 threads/row, 12 ch each ----
    {
        int r = tid >> 2, sub = tid & 3;
        int l = c*CHN + r;
        size_t gb = ((size_t)b*LL + l)*GG;
        float g0[8], g1[8], g2v[8];
        #pragma unroll
        for (int g = 0; g < 8; ++g) { g1[g] = 0.f; g2v[g] = 0.f; }
        load8(g0, gtw + gb);
        if (l >= 1) load8(g1, gtw + gb - GG);
        if (l >= 2) load8(g2v, gtw + gb - 2*GG);
        #pragma unroll
        for (int k = 0; k < 12; ++k) {
            int ch = sub*12 + k;
            float bia = s_ipb2[ch];
            float tA = bia, tB = bia, tC = bia;
            #pragma unroll
            for (int g = 0; g < 8; ++g) {
                float wv = s_ipw[ch*8+g];
                tA = fmaf(g0[g],  wv, tA);
                tB = fmaf(g1[g],  wv, tB);
                tC = fmaf(g2v[g], wv, tC);
            }
            if (l < 1) tB = 0.f;
            if (l < 2) tC = 0.f;
            float a = s_cb2[ch];
            a = fmaf(tC, s_cw2[ch*3+0], a);
            a = fmaf(tB, s_cw2[ch*3+1], a);
            a = fmaf(tA, s_cw2[ch*3+2], a);
            float v = siluf(a);
            if (ch < 16) {
                s_xf[r*20 + ch] = v;
                XTbf[ch*72 + r] = f2bf(v);
            } else if (ch < 32) {
                int n = ch - 16;
                unsigned short bv = f2bf(v);
                Bbf[r*40 + n] = bv;
                BTbf[n*72 + r] = bv;
            } else {
                Cbf[r*40 + (ch - 32)] = f2bf(v);
            }
        }
        // zero K-pad cols 16..31 of Cbf/Bbf row r (each sub covers 2 dwords = 4 u16)
        unsigned int* cz = (unsigned int*)&Cbf[r*40 + 16];
        unsigned int* bz = (unsigned int*)&Bbf[r*40 + 16];
        cz[sub*2+0] = 0u; cz[sub*2+1] = 0u;
        bz[sub*2+0] = 0u; bz[sub*2+1] = 0u;
        if (sub == 0) {
            float d0 = bdt0, d1 = bdt1;
            #pragma unroll
            for (int g = 0; g < 8; ++g) {
                d0 = fmaf(g0[g], s_wdt[g],   d0);
                d1 = fmaf(g0[g], s_wdt[8+g], d1);
            }
            float dt0 = softplusf(d0 + dtb0), dt1 = softplusf(d1 + dtb1);
            s_dt[r][0] = dt0; s_dt[r][1] = dt1;
            s_nda[r][0] = -dt0*a0e; s_nda[r][1] = -dt1*a1e;
        }
    }
    __syncthreads();                                              // B1

    // ---- log-cumsum (wave 0) || cmw coalesced write (all) ----
    if (tid < 64) {
        int rr = tid;
        float v0 = s_nda[rr][0], v1 = s_nda[rr][1];
        #pragma unroll
        for (int off = 1; off < 64; off <<= 1) {
            float t0 = __shfl_up(v0, off);
            float t1 = __shfl_up(v1, off);
            if (rr >= off) { v0 += t0; v1 += t1; }
        }
        s_la[rr][0] = v0; s_la[rr][1] = v1;
        *(float2*)(caw + ((size_t)b*LL + c*CHN + rr)*2) =
            make_float2(__expf(v0), __expf(v1));
        float f0 = __shfl(v0, 63), f1 = __shfl(v1, 63);
        s_w[rr][0] = __expf(f0 - v0) * s_dt[rr][0];
        s_w[rr][1] = __expf(f1 - v1) * s_dt[rr][1];
        if (rr == 63)
            *(float2*)(Acw + ((size_t)b*NCH + c)*2) = make_float2(__expf(f0), __expf(f1));
    }
    {
        int rr = tid >> 2, q = tid & 3;
        float4 cv;
        cv.x = bf2f(Cbf[rr*40 + q*4 + 0]);
        cv.y = bf2f(Cbf[rr*40 + q*4 + 1]);
        cv.z = bf2f(Cbf[rr*40 + q*4 + 2]);
        cv.w = bf2f(Cbf[rr*40 + q*4 + 3]);
        ((float4*)(cmw + ((size_t)b*LL + c*CHN + rr)*16))[q] = cv;
    }
    __syncthreads();                                              // B2

    int lane = tid & 63, wv = tid >> 6;
    int ar = lane & 15;          // A row within tile / D col
    int kb = lane >> 4;          // k-block
    int trow = wv*16 + kb*4;     // D row base for this wave's row-tile

    // ---- G tiles + mask -> M~ (bf16)  ||  wx^T build ----
    {
        bf16x8 aC = *(const bf16x8*)&Cbf[(wv*16 + ar)*40 + kb*8];
        float lr0 = s_la[wv*16][0], lr1 = s_la[wv*16][1];
        float ef0[4], ef1[4];
        #pragma unroll
        for (int rg = 0; rg < 4; ++rg) {
            ef0[rg] = __expf(s_la[trow+rg][0] - lr0);
            ef1[rg] = __expf(s_la[trow+rg][1] - lr1);
        }
        for (int ss = 0; ss < 4; ++ss) {
            int s = ss*16 + ar;
            if (ss > wv) {           // fully masked tile: write zeros (avoid inf*0)
                #pragma unroll
                for (int rg = 0; rg < 4; ++rg) {
                    M0[(trow+rg)*72 + s] = 0;
                    M1[(trow+rg)*72 + s] = 0;
                }
                continue;
            }
            f32x4 g = {0.f, 0.f, 0.f, 0.f};
            bf16x8 bB = *(const bf16x8*)&Bbf[(ss*16 + ar)*40 + kb*8];
            g = __builtin_amdgcn_mfma_f32_16x16x32_bf16(aC, bB, g, 0, 0, 0);
            float ec0 = __expf(lr0 - s_la[s][0]) * s_dt[s][0];
            float ec1 = __expf(lr1 - s_la[s][1]) * s_dt[s][1];
            #pragma unroll
            for (int rg = 0; rg < 4; ++rg) {
                int t = trow + rg;
                float gv = g[rg];
                float m0 = (s <= t) ? ef0[rg]*ec0*gv : 0.f;
                float m1 = (s <= t) ? ef1[rg]*ec1*gv : 0.f;
                M0[t*72 + s] = f2bf(m0);
                M1[t*72 + s] = f2bf(m1);
            }
        }
    }
    #pragma unroll
    for (int i = 0; i < 4; ++i) {        // wx^T: 1024 entries / 256 threads
        int e = tid + 256*i;
        int s = e >> 4, pp = e & 15;
        WXbf[pp*72 + s] = f2bf(s_w[s][pp>>3] * s_xf[s*20 + pp]);
    }
    __syncthreads();                                              // B3

    // ---- Y = M~ . X (+ D*x) via MFMA; bounce through yb (=Cbf space) ----
    float* yb = (float*)Cbf;             // 64x20 f32 == 5120B, Cbf is done
    {
        int p = ar;
        #pragma unroll
        for (int h = 0; h < 2; ++h) {
            const unsigned short* Mh = h ? M1 : M0;
            f32x4 acc = {0.f, 0.f, 0.f, 0.f};
            #pragma unroll
            for (int kk = 0; kk < 2; ++kk) {
                bf16x8 am = *(const bf16x8*)&Mh[(wv*16 + ar)*72 + kk*32 + kb*8];
                bf16x8 bx = {0,0,0,0,0,0,0,0};
                if (p < 8) bx = *(const bf16x8*)&XTbf[(h*8 + p)*72 + kk*32 + kb*8];
                acc = __builtin_amdgcn_mfma_f32_16x16x32_bf16(am, bx, acc, 0, 0, 0);
            }
            if (p < 8) {
                float Dh = h ? D1 : D0;
                #pragma unroll
                for (int rg = 0; rg < 4; ++rg) {
                    int t = trow + rg;
                    yb[t*20 + h*8 + p] = fmaf(Dh, s_xf[t*20 + h*8 + p], acc[rg]);
                }
            }
        }
    }
    // ---- chunk end-state via MFMA (wave 0 only) ----
    if (wv == 0) {
        f32x4 acc = {0.f, 0.f, 0.f, 0.f};
        #pragma unroll
        for (int kk = 0; kk < 2; ++kk) {
            bf16x8 aw = *(const bf16x8*)&WXbf[ar*72 + kk*32 + kb*8];
            bf16x8 bb = *(const bf16x8*)&BTbf[ar*72 + kk*32 + kb*8];
            acc = __builtin_amdgcn_mfma_f32_16x16x32_bf16(aw, bb, acc, 0, 0, 0);
        }
        #pragma unroll
        for (int rg = 0; rg < 4; ++rg) {
            int pr = kb*4 + rg;
            U2w[(((size_t)b*NCH + c) << 8) + pr*16 + ar] = acc[rg];
        }
    }
    __syncthreads();                                              // B4

    {   // coalesced yl store
        int rr = tid >> 2, q = tid & 3;
        ((float4*)(ylw + ((size_t)b*LL + c*CHN + rr)*16))[q] = *(float4*)&yb[rr*20 + q*4];
    }
}

// K4c1: scan 16 chunks within each group (states preloaded -> 1 latency).
__global__ void k4c1(const float* __restrict__ U2w, const float* __restrict__ Acw,
                     float* __restrict__ phw, float* __restrict__ cpw,
                     float* __restrict__ Ugw, float* __restrict__ Agw)
{
    int b = blockIdx.x >> 4, grp = blockIdx.x & 15;
    int e = threadIdx.x, he = e >> 7;
    size_t base = (size_t)b*NCH + grp*16;
    float u[16], A[16];
    #pragma unroll
    for (int j = 0; j < 16; ++j) u[j] = U2w[((base + j) << 8) + e];
    #pragma unroll
    for (int j = 0; j < 16; ++j) A[j] = Acw[(base + j)*2 + he];
    float h = 0.f, cp = 1.f;
    #pragma unroll
    for (int j = 0; j < 16; ++j) {
        phw[((base + j) << 8) + e] = h;
        if ((e & 127) == 0) cpw[(base + j)*2 + he] = cp;
        h = fmaf(A[j], h, u[j]);
        cp *= A[j];
    }
    Ugw[(((size_t)b*NGRP + grp) << 8) + e] = h;
    if ((e & 127) == 0) Agw[((size_t)b*NGRP + grp)*2 + he] = cp;
}

// K4c2: scan 16 group summaries.
__global__ void k4c2(const float* __restrict__ Ugw, const float* __restrict__ Agw,
                     float* __restrict__ ghw)
{
    int b = blockIdx.x, e = threadIdx.x, he = e >> 7;
    float u[NGRP], ag[NGRP];
    #pragma unroll
    for (int g = 0; g < NGRP; ++g) {
        u[g]  = Ugw[(((size_t)b*NGRP + g) << 8) + e];
        ag[g] = Agw[((size_t)b*NGRP + g)*2 + he];
    }
    float h = 0.f;
    #pragma unroll
    for (int g = 0; g < NGRP; ++g) {
        ghw[(((size_t)b*NGRP + g) << 8) + e] = h;
        h = fmaf(ag[g], h, u[g]);
    }
}

// K5a: hin reconstruction + correction + silu(z) gate + RMSNorm + out proj + gt residual -> g2
__global__ __launch_bounds__(256, 4) void k5a_epi(
    const float* __restrict__ gtw, const float* __restrict__ cmw,
    const float* __restrict__ ylw, const float* __restrict__ caw,
    const float* __restrict__ phw, const float* __restrict__ cpw,
    const float* __restrict__ ghw,
    const float* __restrict__ ipw, const float* __restrict__ ipb,
    const float* __restrict__ norm_w,
    const float* __restrict__ out_w, const float* __restrict__ out_b,
    float* __restrict__ g2w)
{
    __shared__ float s_hin[4][256];
    __shared__ float s_zw[16*GG], s_ow[GG*16];
    int tid = threadIdx.x;
    int b  = blockIdx.x >> 6;
    int ck = blockIdx.x & 63;           // 256-row block = 4 chunks of 64
    int grpg = ck >> 2;
    float gh = ghw[(((size_t)b*NGRP + grpg) << 8) + tid];
    #pragma unroll
    for (int k = 0; k < 4; ++k) {
        int chn = ck*4 + k;
        float cpv = cpw[((size_t)b*NCH + chn)*2 + (tid >> 7)];
        s_hin[k][tid] = fmaf(cpv, gh, phw[(((size_t)b*NCH + chn) << 8) + tid]);
    }
    if (tid < 128) s_zw[tid] = ipw[tid];
    else s_ow[tid-128] = out_w[tid-128];
    __syncthreads();
    size_t pb = (size_t)b*LL + (ck<<8) + tid;
    int sub = tid >> 6;
    float gv[8]; load8(gv, gtw + pb*GG);
    float Cv[16], ylv[16];
    load16(Cv,  cmw + pb*16);
    load16(ylv, ylw + pb*16);
    float2 ca = *(const float2*)(caw + pb*2);
    float vv[16], ss = 0.f;
    #pragma unroll
    for (int hp = 0; hp < 16; ++hp) {
        float dot = 0.f;
        #pragma unroll
        for (int nn = 0; nn < 16; ++nn)
            dot = fmaf(Cv[nn], s_hin[sub][(hp>>3)*128 + (hp&7)*16 + nn], dot);
        float zz = ipb[hp];
        #pragma unroll
        for (int g = 0; g < GG; ++g) zz = fmaf(gv[g], s_zw[hp*GG+g], zz);
        float y = fmaf((hp>>3) ? ca.y : ca.x, dot, ylv[hp]);
        float w = y * siluf(zz);
        vv[hp] = w; ss = fmaf(w, w, ss);
    }
    float rn = rsqrtf(ss*(1.f/16.f) + 1e-5f);
    float o[8];
    #pragma unroll
    for (int g = 0; g < GG; ++g) o[g] = out_b[g] + gv[g];
    #pragma unroll
    for (int hp = 0; hp < 16; ++hp) {
        float wv = vv[hp] * rn * norm_w[hp];
        #pragma unroll
        for (int g = 0; g < GG; ++g) o[g] = fmaf(wv, s_ow[g*16+hp], o[g]);
    }
    float* gp = g2w + pb*GG;
    ((float4*)gp)[0] = make_float4(o[0],o[1],o[2],o[3]);
    ((float4*)gp)[1] = make_float4(o[4],o[5],o[6],o[7]);
}

// K5b: out = x + detok(g2) + detok_b.  1024 blocks x 64 threads, 4 l per thread.
__global__ __launch_bounds__(64) void k5b_detok(
    const float* __restrict__ x, const float* __restrict__ g2w,
    const float* __restrict__ dkw, const float* __restrict__ dkb,
    float* __restrict__ outp)
{
    __shared__ float s_dw[CF*GG];
    __shared__ float s_db[CF];
    int tid = threadIdx.x;
    int b  = blockIdx.x >> 6;
    int ck = blockIdx.x & 63;
    int l0 = (ck << 8) + (tid << 2);
    for (int i = tid; i < CF*GG; i += 64) s_dw[i] = dkw[i];
    s_db[tid] = dkb[tid];
    __syncthreads();
    float g2v[4][8];
    const float* gp = g2w + ((size_t)b*LL + l0)*GG;
    #pragma unroll
    for (int r = 0; r < 4; ++r) load8(g2v[r], gp + r*GG);
    const float* xb = x + (size_t)b*CF*LL + l0;
    float* ob = outp + (size_t)b*CF*LL + l0;
    #pragma unroll 4
    for (int c = 0; c < CF; ++c) {
        float4 xv = *(const float4*)(xb + (size_t)c*LL);
        float bias = s_db[c];
        float oa[4] = {xv.x+bias, xv.y+bias, xv.z+bias, xv.w+bias};
        #pragma unroll
        for (int g = 0; g < GG; ++g) {
            float w = s_dw[c*GG+g];
            #pragma unroll
            for (int r = 0; r < 4; ++r) oa[r] = fmaf(g2v[r][g], w, oa[r]);
        }
        *(float4*)(ob + (size_t)c*LL) = make_float4(oa[0],oa[1],oa[2],oa[3]);
    }
}

extern "C" void kernel_launch(void* const* d_in, const int* in_sizes, int n_in,
                              void* d_out, int out_size, void* d_ws, size_t ws_size,
                              hipStream_t stream) {
    const float* x       = (const float*)d_in[0];
    const float* tok_w   = (const float*)d_in[1];
    const float* tok_b   = (const float*)d_in[2];
    const float* detok_w = (const float*)d_in[3];
    const float* detok_b = (const float*)d_in[4];
    const float* ipw     = (const float*)d_in[5];
    const float* ipb     = (const float*)d_in[6];
    const float* cw      = (const float*)d_in[7];
    const float* cb      = (const float*)d_in[8];
    const float* A_log   = (const float*)d_in[9];
    const float* Dv      = (const float*)d_in[10];
    const float* dt_bias = (const float*)d_in[11];
    const float* norm_w  = (const float*)d_in[12];
    const float* out_w   = (const float*)d_in[13];
    const float* out_b   = (const float*)d_in[14];
    float* ws = (float*)d_ws;
    float* outp = (float*)d_out;

    if (ws_size < WS_FLOATS * sizeof(float)) return;

    k1a_tok<<<NB*64, 64, 0, stream>>>(x, tok_w, tok_b, ws+OFF_GT);
    k2_ssd<<<NB*NCH, 256, 0, stream>>>(ws+OFF_GT, ipw, ipb, cw, cb,
        A_log, dt_bias, Dv, ws+OFF_C, ws+OFF_YL, ws+OFF_CA, ws+OFF_U2, ws+OFF_AC);
    k4c1<<<NB*NGRP, 256, 0, stream>>>(ws+OFF_U2, ws+OFF_AC,
        ws+OFF_PH, ws+OFF_CP, ws+OFF_UG, ws+OFF_AG);
    k4c2<<<NB, 256, 0, stream>>>(ws+OFF_UG, ws+OFF_AG, ws+OFF_GH);
    k5a_epi<<<NB*64, 256, 0, stream>>>(ws+OFF_GT, ws+OFF_C, ws+OFF_YL, ws+OFF_CA,
        ws+OFF_PH, ws+OFF_CP, ws+OFF_GH, ipw, ipb, norm_w, out_w, out_b, ws+OFF_G2);
    k5b_detok<<<NB*64, 64, 0, stream>>>(x, ws+OFF_G2, detok_w, detok_b, outp);
}